// Round 12
// baseline (179.052 us; speedup 1.0000x reference)
//
#include <hip/hip_runtime.h>
#include <hip/hip_bf16.h>

#define N_NODES 100000
#define N_EDGES 1600000
#define NT32    3125           // 100000/32 exactly
#define PRE_BLKS 625           // 625*5 = 3125 tiles, 3 blocks/CU -> 1 round

// ws layout: Aq @0 (12.8 MB) | Bq @12.8M (12.8 MB) | sA @25.6M | sB @26.0M
#define BQ_OFF 12800000
#define SA_OFF 25600000
#define SB_OFF 26000000

typedef __attribute__((ext_vector_type(8))) short short8v;   // 8 bf16 = 4 VGPRs
typedef __attribute__((ext_vector_type(4))) float float4v;   // MFMA C/D

// ---------- bf16 helpers ----------
__device__ __forceinline__ unsigned short f2bf(float f) {
    unsigned int u = __float_as_uint(f);
    u += 0x7fffu + ((u >> 16) & 1u);   // round-to-nearest-even
    return (unsigned short)(u >> 16);
}
__device__ __forceinline__ unsigned int pack2bf(float a, float b) {
    return (unsigned int)f2bf(a) | ((unsigned int)f2bf(b) << 16);
}
__device__ __forceinline__ short8v pack8rne(float4 a, float4 b) {
    union { unsigned int w[4]; short8v s; } u;
    u.w[0] = pack2bf(a.x, a.y); u.w[1] = pack2bf(a.z, a.w);
    u.w[2] = pack2bf(b.x, b.y); u.w[3] = pack2bf(b.z, b.w);
    return u.s;
}
// magic-add quantize: biased uint8 (round(f*inv)+128) in the LOW BYTE, RNE.
#define MAGICB 12583040.0f     // 2^23 + 2^22 + 128
__device__ __forceinline__ unsigned int qmagic(float f, float inv) {
    return __float_as_uint(fmaf(f, inv, MAGICB));
}

// ---------------------------------------------------------------------------
// Phase 1 (MFMA, W-in-registers, merged halves, persistent):
//   Aq[n][c] = q128(x[n]@W1[c,:128] + b1[c]),  sA[n] = rowmax/127
//   Bq[n][c] = q128(x[n]@W1[c,128:]),          sB[n] = rowmax/127
// Wave w owns concat-cols [w*64, w*64+64) and holds its W fragment in
// REGISTERS (16 short8v = 64 VGPR, loaded once per block from L2-resident
// W1, RNE-packed -> numerics identical to the LDS-staged version).
// x is read ONCE (vs twice in the col-half-split grid). Per 32-node tile:
//   stage x->LDS | MFMA (xf ds_reads only) | +b1 (waves 0,1) | per-node
//   max: quad shfl + one cross-wave LDS combine | quantize DIRECTLY from
//   acc regs -> byte staging LDS (stride 272 B: 2-way banks = free) |
//   coalesced 16-B stores. 4 barriers/tile (was 7).
// 625 blocks x 5 tiles, 100000 = 3125*32 -> zero bounds checks.
// ---------------------------------------------------------------------------
__global__ __launch_bounds__(256, 3) void precompute_kernel(
    const float* __restrict__ x, const float* __restrict__ W1,
    const float* __restrict__ b1, unsigned char* __restrict__ Aq,
    unsigned char* __restrict__ Bq, float* __restrict__ sA,
    float* __restrict__ sB) {
    __shared__ unsigned short xlds[32 * 132];   // 8448 B, x tile (bf16)
    __shared__ unsigned int bytebuf[32 * 68];   // 8704 B, quant staging
    __shared__ float wmax[4][32];               // per-wave per-node max

    const int tid = threadIdx.x;
    const int wave = tid >> 6, lane = tid & 63;
    const int quad = lane >> 4, l15 = lane & 15;

    // ---- W fragment into registers: wf[j][s] covers cols jcb+j*16+l15,
    //      k = khalf + s*32 + quad*8 .. +8  (A-operand layout)
    const int jcb = wave * 64;            // concat col base
    const int wrow = jcb & 127;           // W1 row base
    const int khalf = (jcb >> 7) * 128;   // 0 (A) or 128 (B)
    short8v wf[4][4];
#pragma unroll
    for (int j = 0; j < 4; ++j)
#pragma unroll
        for (int s = 0; s < 4; ++s) {
            const float4* p = reinterpret_cast<const float4*>(
                W1 + (size_t)(wrow + j * 16 + l15) * 256 + khalf + s * 32 + quad * 8);
            wf[j][s] = pack8rne(p[0], p[1]);
        }

    // b1 for A-half waves (added in fp32 after MFMA, before quant)
    float4 b1v[4];
    if (wave < 2) {
#pragma unroll
        for (int j = 0; j < 4; ++j)
            b1v[j] = *reinterpret_cast<const float4*>(b1 + jcb + j * 16 + quad * 4);
    }

    // ---- prologue: first tile's x into regs (32 nodes x 128 fp32)
    float4 xr[4];
    int t = blockIdx.x;
#pragma unroll
    for (int i = 0; i < 4; ++i) {
        int fi = tid + i * 256;           // float4 idx 0..1023
        int n = fi >> 5, c4 = fi & 31;
        xr[i] = reinterpret_cast<const float4*>(x)[(size_t)(t * 32 + n) * 32 + c4];
    }

    for (; t < NT32; t += PRE_BLKS) {
        __syncthreads();   // S1: xlds + bytebuf free (prev tile fully drained)
#pragma unroll
        for (int i = 0; i < 4; ++i) {
            int fi = tid + i * 256;
            int n = fi >> 5, c4 = fi & 31;
            unsigned int* d = reinterpret_cast<unsigned int*>(&xlds[n * 132 + c4 * 4]);
            d[0] = pack2bf(xr[i].x, xr[i].y);
            d[1] = pack2bf(xr[i].z, xr[i].w);
        }
        __syncthreads();   // S2: x tile staged

        const int tn = t + PRE_BLKS;
        if (tn < NT32) {
#pragma unroll
            for (int i = 0; i < 4; ++i) {
                int fi = tid + i * 256;
                int n = fi >> 5, c4 = fi & 31;
                xr[i] = reinterpret_cast<const float4*>(x)[(size_t)(tn * 32 + n) * 32 + c4];
            }
        }

        // ---- MFMA: acc[i: node-tile][j: col-tile], K=128 in 4 steps
        float4v acc[2][4];
#pragma unroll
        for (int i = 0; i < 2; ++i)
#pragma unroll
            for (int j = 0; j < 4; ++j) acc[i][j] = float4v{0.f, 0.f, 0.f, 0.f};

#pragma unroll
        for (int s = 0; s < 4; ++s) {
            const int k0 = s * 32 + quad * 8;
            short8v xf[2];
#pragma unroll
            for (int i = 0; i < 2; ++i)
                xf[i] = *reinterpret_cast<const short8v*>(&xlds[(i * 16 + l15) * 132 + k0]);
#pragma unroll
            for (int i = 0; i < 2; ++i)
#pragma unroll
                for (int j = 0; j < 4; ++j)
                    acc[i][j] = __builtin_amdgcn_mfma_f32_16x16x32_bf16(wf[j][s], xf[i], acc[i][j], 0, 0, 0);
        }

        // ---- +b1 (A-half waves), then per-node abs-max over this wave's cols
        if (wave < 2) {
#pragma unroll
            for (int i = 0; i < 2; ++i)
#pragma unroll
                for (int j = 0; j < 4; ++j) {
                    acc[i][j][0] += b1v[j].x; acc[i][j][1] += b1v[j].y;
                    acc[i][j][2] += b1v[j].z; acc[i][j][3] += b1v[j].w;
                }
        }
        float m[2];
#pragma unroll
        for (int i = 0; i < 2; ++i) {
            m[i] = 1e-6f;
#pragma unroll
            for (int j = 0; j < 4; ++j)
#pragma unroll
                for (int r = 0; r < 4; ++r)
                    m[i] = fmaxf(m[i], fabsf(acc[i][j][r]));
            m[i] = fmaxf(m[i], __shfl_xor(m[i], 16));   // reduce over quad
            m[i] = fmaxf(m[i], __shfl_xor(m[i], 32));
        }
        if (quad == 0) { wmax[wave][l15] = m[0]; wmax[wave][16 + l15] = m[1]; }
        __syncthreads();   // S3: wmax readable

        float inv[2];
#pragma unroll
        for (int i = 0; i < 2; ++i) {
            float mh = fmaxf(m[i], wmax[wave ^ 1][i * 16 + l15]);
            inv[i] = 127.0f / mh;
            if (quad == 0 && (wave == 0 || wave == 2)) {
                float* S = (wave == 0) ? sA : sB;
                S[t * 32 + i * 16 + l15] = mh * (1.0f / 127.0f);
            }
        }

        // ---- quantize from regs -> byte staging (stride 68 dwords = 272 B)
#pragma unroll
        for (int i = 0; i < 2; ++i)
#pragma unroll
            for (int j = 0; j < 4; ++j) {
                unsigned int q0 = qmagic(acc[i][j][0], inv[i]);
                unsigned int q1 = qmagic(acc[i][j][1], inv[i]);
                unsigned int q2 = qmagic(acc[i][j][2], inv[i]);
                unsigned int q3 = qmagic(acc[i][j][3], inv[i]);
                unsigned int pk = (q0 & 0xffu) | ((q1 & 0xffu) << 8) |
                                  ((q2 & 0xffu) << 16) | (q3 << 24);
                bytebuf[(i * 16 + l15) * 68 + wave * 16 + j * 4 + quad] = pk;
            }
        __syncthreads();   // S4: bytes staged

        // ---- coalesced store: row = tid>>3 (32 nodes), part = tid&7
        {
            const int row = tid >> 3, part = tid & 7;
            const unsigned int* src = &bytebuf[row * 68 + part * 8];
            uint4 o0 = *reinterpret_cast<const uint4*>(src);
            uint4 o1 = *reinterpret_cast<const uint4*>(src + 4);
            const int n = t * 32 + row;
            unsigned char* dst = (part < 4) ? Aq : Bq;
            const int cb = (part & 3) * 32;
            *reinterpret_cast<uint4*>(dst + (size_t)n * 128 + cb) = o0;
            *reinterpret_cast<uint4*>(dst + (size_t)n * 128 + cb + 16) = o1;
        }
    }
}

// ---------------------------------------------------------------------------
// Phase 2: out[e] = W2 . relu(dq(Aq[u]) + dq(Bq[v])) + b2
// Biased uint8: relu(A+B) = su * max(fma(ub, r, ua) - c, 0), r = sv/su,
// c = 128(1+r); su applied once after the 4-lane reduction.
// 4 lanes/edge, 16 edges/wave-iter, 8x16-B gathers in flight.
// __launch_bounds__(256,4): R8/R10-verified — (256,8) raised WRITE_SIZE
// 6.4->21 MB via partial-line out writebacks (R9 regression).
// Parked at the compulsory per-XCD fetch floor (~189 MB @ ~3.2 TB/s).
// ---------------------------------------------------------------------------
template <bool IS64>
__device__ __forceinline__ void edge_loop(
    const long long* __restrict__ ei, const unsigned char* __restrict__ Aq,
    const unsigned char* __restrict__ Bq, const float* __restrict__ sA,
    const float* __restrict__ sB, const float* __restrict__ W2, float bias2,
    float* __restrict__ out, int wid, int nwaves, int eg, int sl) {
    const int k0 = sl * 32;              // feature base for this lane
    float w2f[32];
#pragma unroll
    for (int j = 0; j < 8; ++j)
        *reinterpret_cast<float4*>(&w2f[j * 4]) =
            *reinterpret_cast<const float4*>(W2 + k0 + j * 4);
    const int* e32 = reinterpret_cast<const int*>(ei);

    for (int base = wid * 16; base < N_EDGES; base += nwaves * 16) {
        const int e = base + eg;          // N_EDGES % 16 == 0 -> in range
        int u, v;
        if (IS64) { u = (int)ei[e]; v = (int)ei[N_EDGES + e]; }
        else      { u = e32[e];     v = e32[N_EDGES + e]; }

        const uint4* pa = reinterpret_cast<const uint4*>(Aq + (unsigned)u * 128 + k0);
        const uint4* pb = reinterpret_cast<const uint4*>(Bq + (unsigned)v * 128 + k0);
        uint4 a0 = pa[0], a1 = pa[1];
        uint4 b0 = pb[0], b1w = pb[1];
        const float su = sA[u];
        const float sv = sB[v];
        const float r = sv * __builtin_amdgcn_rcpf(su);   // su > 0 by construction
        const float c = fmaf(r, 128.0f, 128.0f);          // 128*(1+r)

        unsigned int aw[8] = {a0.x, a0.y, a0.z, a0.w, a1.x, a1.y, a1.z, a1.w};
        unsigned int bw[8] = {b0.x, b0.y, b0.z, b0.w, b1w.x, b1w.y, b1w.z, b1w.w};

        float p = 0.f;
#pragma unroll
        for (int wi = 0; wi < 8; ++wi) {
#pragma unroll
            for (int byt = 0; byt < 4; ++byt) {
                float fa = (float)((aw[wi] >> (8 * byt)) & 0xffu);  // v_cvt_f32_ubyteN
                float fb = (float)((bw[wi] >> (8 * byt)) & 0xffu);
                float s = fmaxf(fmaf(fb, r, fa) - c, 0.f);
                p = fmaf(s, w2f[wi * 4 + byt], p);
            }
        }
        p += __shfl_xor(p, 1);
        p += __shfl_xor(p, 2);
        if (sl == 0) out[e] = fmaf(su, p, bias2);
    }
}

__global__ __launch_bounds__(256, 4) void edge_kernel(
    const long long* __restrict__ ei, const unsigned char* __restrict__ Aq,
    const unsigned char* __restrict__ Bq, const float* __restrict__ sA,
    const float* __restrict__ sB, const float* __restrict__ W2,
    const float* __restrict__ b2, float* __restrict__ out) {
    const int lane = threadIdx.x & 63;
    const int eg = lane >> 2;     // edge group 0..15 within wave
    const int sl = lane & 3;      // sub-lane within edge
    const float bias2 = b2[0];

    // int64-vs-int32 edge_index robustness probe (values < 1e5 -> hi words 0)
    const unsigned int hi = reinterpret_cast<const unsigned int*>(ei)[2 * lane + 1];
    const bool is64 = (__ballot(hi != 0) == 0ull);

    const int wid = (int)(((unsigned)(blockIdx.x * blockDim.x + threadIdx.x)) >> 6);
    const int nwaves = (int)(((unsigned)(gridDim.x * blockDim.x)) >> 6);

    if (is64) edge_loop<true>(ei, Aq, Bq, sA, sB, W2, bias2, out, wid, nwaves, eg, sl);
    else      edge_loop<false>(ei, Aq, Bq, sA, sB, W2, bias2, out, wid, nwaves, eg, sl);
}

extern "C" void kernel_launch(void* const* d_in, const int* in_sizes, int n_in,
                              void* d_out, int out_size, void* d_ws, size_t ws_size,
                              hipStream_t stream) {
    const float* x = (const float*)d_in[0];
    const long long* ei = (const long long*)d_in[1];
    const float* W1 = (const float*)d_in[2];
    const float* b1 = (const float*)d_in[3];
    const float* W2 = (const float*)d_in[4];
    const float* b2 = (const float*)d_in[5];
    float* out = (float*)d_out;

    unsigned char* Aq = (unsigned char*)d_ws;
    unsigned char* Bq = (unsigned char*)d_ws + BQ_OFF;
    float* sA = (float*)((char*)d_ws + SA_OFF);
    float* sB = (float*)((char*)d_ws + SB_OFF);

    precompute_kernel<<<PRE_BLKS, 256, 0, stream>>>(x, W1, b1, Aq, Bq, sA, sB);
    edge_kernel<<<2048, 256, 0, stream>>>(ei, Aq, Bq, sA, sB, W2, b2, out);
}

// Round 13
// 176.190 us; speedup vs baseline: 1.0162x; 1.0162x over previous
//
#include <hip/hip_runtime.h>
#include <hip/hip_bf16.h>

#define N_NODES 100000
#define N_EDGES 1600000
#define NT_TILES 1563          // ceil(N_NODES/64)
#define PRE_BLKX 384           // 384*2 = 768 blocks = 3 blocks/CU residency

// ws layout: Aq @0 (12.8 MB) | Bq @12.8M (12.8 MB) | sA @25.6M | sB @26.0M
#define BQ_OFF 12800000
#define SA_OFF 25600000
#define SB_OFF 26000000

typedef __attribute__((ext_vector_type(8))) short short8v;   // 8 bf16 = 4 VGPRs
typedef __attribute__((ext_vector_type(4))) float float4v;   // MFMA C/D

// ---------- bf16 helpers ----------
__device__ __forceinline__ unsigned short f2bf(float f) {
    unsigned int u = __float_as_uint(f);
    u += 0x7fffu + ((u >> 16) & 1u);   // round-to-nearest-even
    return (unsigned short)(u >> 16);
}
__device__ __forceinline__ unsigned int pack2bf(float a, float b) {
    return (unsigned int)f2bf(a) | ((unsigned int)f2bf(b) << 16);
}
__device__ __forceinline__ float2 bfpair(unsigned int w) {
    return float2{__uint_as_float(w << 16), __uint_as_float(w & 0xffff0000u)};
}
__device__ __forceinline__ short8v pack8rne(float4 a, float4 b) {
    union { unsigned int w[4]; short8v s; } u;
    u.w[0] = pack2bf(a.x, a.y); u.w[1] = pack2bf(a.z, a.w);
    u.w[2] = pack2bf(b.x, b.y); u.w[3] = pack2bf(b.z, b.w);
    return u.s;
}
// magic-add quantize: biased uint8 (round(f*inv)+128) in the LOW BYTE, RNE.
#define MAGICB 12583040.0f     // 2^23 + 2^22 + 128
__device__ __forceinline__ unsigned int qmagic(float f, float inv) {
    return __float_as_uint(fmaf(f, inv, MAGICB));
}

// ---------------------------------------------------------------------------
// Phase 1 (MFMA, persistent node-loop) + biased-uint8 row quantization:
//   by==0: Aq[n][c] = q128(x[n]@W1[c,:128] + b1[c]),  sA[n] = rowmax/127
//   by==1: Bq[n][c] = q128(x[n]@W1[c,128:]),          sB[n] = rowmax/127
// R11 structure verbatim EXCEPT: the wave's W fragment lives in REGISTERS
// (8 short8v = 32 VGPR; each lane needs only its own quad's k-slices),
// loaded once per block from the L2-resident W1 with the same RNE pack ->
// numerics bit-identical to the LDS-staged version. LDS drops 52.2->17.4 KB;
// MFMA-loop ds_reads drop 6->4 per K-step (xf only).
// ---------------------------------------------------------------------------
__global__ __launch_bounds__(256) void precompute_kernel(
    const float* __restrict__ x, const float* __restrict__ W1,
    const float* __restrict__ b1, unsigned char* __restrict__ Aq,
    unsigned char* __restrict__ Bq, float* __restrict__ sA,
    float* __restrict__ sB) {
    __shared__ unsigned short xlds[64 * 136];   // input tile AND acc staging

    const int tid = threadIdx.x;
    const int by = blockIdx.y;            // 0: A-half (+b1), 1: B-half
    unsigned char* __restrict__ Q = by ? Bq : Aq;
    float* __restrict__ S = by ? sB : sA;

    const int wave = tid >> 6;
    const int lane = tid & 63;
    const int quad = lane >> 4;
    const int l15 = lane & 15;

    float4 b1v[2];
#pragma unroll
    for (int j = 0; j < 2; ++j)
        b1v[j] = *reinterpret_cast<const float4*>(b1 + wave * 32 + j * 16 + quad * 4);

    // ---- W fragment into registers (once per block):
    // wf[j][s] = W1[wave*32 + j*16 + l15][by*128 + s*32 + quad*8 .. +8]
    // (identical data the ds_read_b128 from wlds delivered in R11)
    short8v wf[2][4];
#pragma unroll
    for (int j = 0; j < 2; ++j)
#pragma unroll
        for (int s = 0; s < 4; ++s) {
            const float4* p = reinterpret_cast<const float4*>(
                W1 + (size_t)(wave * 32 + j * 16 + l15) * 256 + by * 128 + s * 32 + quad * 8);
            wf[j][s] = pack8rne(p[0], p[1]);
        }

    // ---- prologue: first tile's x into regs
    float4 xr[8];
    int t = blockIdx.x;
#pragma unroll
    for (int i = 0; i < 8; ++i) {
        int fi = tid + i * 256;
        int n = fi >> 5, c4 = fi & 31;
        int nn = t * 64 + n; nn = nn < N_NODES ? nn : N_NODES - 1;
        xr[i] = reinterpret_cast<const float4*>(x)[(size_t)nn * 32 + c4];
    }

    for (; t < NT_TILES; t += PRE_BLKX) {
        __syncthreads();   // prev epilogue's LDS reads done
#pragma unroll
        for (int i = 0; i < 8; ++i) {
            int fi = tid + i * 256;
            int n = fi >> 5, c4 = fi & 31;
            unsigned int* d = reinterpret_cast<unsigned int*>(&xlds[n * 136 + c4 * 4]);
            d[0] = pack2bf(xr[i].x, xr[i].y);
            d[1] = pack2bf(xr[i].z, xr[i].w);
        }
        __syncthreads();

        const int tn = t + PRE_BLKX;
        if (tn < NT_TILES) {
#pragma unroll
            for (int i = 0; i < 8; ++i) {
                int fi = tid + i * 256;
                int n = fi >> 5, c4 = fi & 31;
                int nn = tn * 64 + n; nn = nn < N_NODES ? nn : N_NODES - 1;
                xr[i] = reinterpret_cast<const float4*>(x)[(size_t)nn * 32 + c4];
            }
        }

        float4v acc[4][2];
#pragma unroll
        for (int i = 0; i < 4; ++i)
#pragma unroll
            for (int j = 0; j < 2; ++j) acc[i][j] = float4v{0.f, 0.f, 0.f, 0.f};

#pragma unroll
        for (int s = 0; s < 4; ++s) {
            const int k0 = s * 32 + quad * 8;
            short8v xf[4];
#pragma unroll
            for (int i = 0; i < 4; ++i)
                xf[i] = *reinterpret_cast<const short8v*>(&xlds[(i * 16 + l15) * 136 + k0]);
#pragma unroll
            for (int i = 0; i < 4; ++i)
#pragma unroll
                for (int j = 0; j < 2; ++j)
                    acc[i][j] = __builtin_amdgcn_mfma_f32_16x16x32_bf16(wf[j][s], xf[i], acc[i][j], 0, 0, 0);
        }
        __syncthreads();   // all xlds input reads done -> reuse as staging

        // ---- acc (+b1) -> LDS staging, bf16, stride 132 shorts
#pragma unroll
        for (int i = 0; i < 4; ++i) {
            const int nl = i * 16 + l15;
#pragma unroll
            for (int j = 0; j < 2; ++j) {
                const int colb = wave * 32 + j * 16 + quad * 4;
                float r0 = acc[i][j][0], r1 = acc[i][j][1];
                float r2 = acc[i][j][2], r3 = acc[i][j][3];
                if (by == 0) {
                    r0 += b1v[j].x; r1 += b1v[j].y;
                    r2 += b1v[j].z; r3 += b1v[j].w;
                }
                uint2 st = {pack2bf(r0, r1), pack2bf(r2, r3)};
                *reinterpret_cast<uint2*>(&xlds[nl * 132 + colb]) = st;
            }
        }
        __syncthreads();

        // ---- per-row max + magic quantize; thread = (row = tid>>2, part = tid&3)
        const int row = tid >> 2, part = tid & 3;
        const int n = t * 64 + row;
        uint4 wv[4];
#pragma unroll
        for (int q = 0; q < 4; ++q)
            wv[q] = *reinterpret_cast<const uint4*>(&xlds[row * 132 + part * 32 + q * 8]);

        float m = 1e-6f;
#pragma unroll
        for (int q = 0; q < 4; ++q) {
            unsigned int ws[4] = {wv[q].x, wv[q].y, wv[q].z, wv[q].w};
#pragma unroll
            for (int w = 0; w < 4; ++w) {
                float2 f = bfpair(ws[w]);
                m = fmaxf(m, fmaxf(fabsf(f.x), fabsf(f.y)));
            }
        }
        m = fmaxf(m, __shfl_xor(m, 1));   // quad (4 parts of one row) reduce
        m = fmaxf(m, __shfl_xor(m, 2));
        const float inv = 127.0f / m;

        unsigned int ob[8];
#pragma unroll
        for (int q = 0; q < 4; ++q) {
            unsigned int ws[4] = {wv[q].x, wv[q].y, wv[q].z, wv[q].w};
#pragma unroll
            for (int w = 0; w < 2; ++w) {
                float2 f0 = bfpair(ws[2 * w + 0]);
                float2 f1 = bfpair(ws[2 * w + 1]);
                unsigned int q0 = qmagic(f0.x, inv), q1 = qmagic(f0.y, inv);
                unsigned int q2 = qmagic(f1.x, inv), q3 = qmagic(f1.y, inv);
                ob[q * 2 + w] = (q0 & 0xffu) | ((q1 & 0xffu) << 8) |
                                ((q2 & 0xffu) << 16) | (q3 << 24);
            }
        }
        if (n < N_NODES) {
            uint4 s0 = {ob[0], ob[1], ob[2], ob[3]};
            uint4 s1 = {ob[4], ob[5], ob[6], ob[7]};
            uint4* dst = reinterpret_cast<uint4*>(Q + (size_t)n * 128 + part * 32);
            dst[0] = s0;
            dst[1] = s1;
            if (part == 0) S[n] = m * (1.0f / 127.0f);
        }
    }
}

// ---------------------------------------------------------------------------
// Phase 2: out[e] = W2 . relu(dq(Aq[u]) + dq(Bq[v])) + b2
// Biased uint8: relu(A+B) = su * max(fma(ub, r, ua) - c, 0), r = sv/su,
// c = 128(1+r); su applied once after the 4-lane reduction.
// 4 lanes/edge, 16 edges/wave-iter, 8x16-B gathers in flight.
// __launch_bounds__(256,4): R8/R10-verified — (256,8) raised WRITE_SIZE
// 6.4->21 MB via partial-line out writebacks (R9 regression).
// Parked at the compulsory per-XCD fetch floor (~189 MB @ ~3.2 TB/s).
// ---------------------------------------------------------------------------
template <bool IS64>
__device__ __forceinline__ void edge_loop(
    const long long* __restrict__ ei, const unsigned char* __restrict__ Aq,
    const unsigned char* __restrict__ Bq, const float* __restrict__ sA,
    const float* __restrict__ sB, const float* __restrict__ W2, float bias2,
    float* __restrict__ out, int wid, int nwaves, int eg, int sl) {
    const int k0 = sl * 32;              // feature base for this lane
    float w2f[32];
#pragma unroll
    for (int j = 0; j < 8; ++j)
        *reinterpret_cast<float4*>(&w2f[j * 4]) =
            *reinterpret_cast<const float4*>(W2 + k0 + j * 4);
    const int* e32 = reinterpret_cast<const int*>(ei);

    for (int base = wid * 16; base < N_EDGES; base += nwaves * 16) {
        const int e = base + eg;          // N_EDGES % 16 == 0 -> in range
        int u, v;
        if (IS64) { u = (int)ei[e]; v = (int)ei[N_EDGES + e]; }
        else      { u = e32[e];     v = e32[N_EDGES + e]; }

        const uint4* pa = reinterpret_cast<const uint4*>(Aq + (unsigned)u * 128 + k0);
        const uint4* pb = reinterpret_cast<const uint4*>(Bq + (unsigned)v * 128 + k0);
        uint4 a0 = pa[0], a1 = pa[1];
        uint4 b0 = pb[0], b1w = pb[1];
        const float su = sA[u];
        const float sv = sB[v];
        const float r = sv * __builtin_amdgcn_rcpf(su);   // su > 0 by construction
        const float c = fmaf(r, 128.0f, 128.0f);          // 128*(1+r)

        unsigned int aw[8] = {a0.x, a0.y, a0.z, a0.w, a1.x, a1.y, a1.z, a1.w};
        unsigned int bw[8] = {b0.x, b0.y, b0.z, b0.w, b1w.x, b1w.y, b1w.z, b1w.w};

        float p = 0.f;
#pragma unroll
        for (int wi = 0; wi < 8; ++wi) {
#pragma unroll
            for (int byt = 0; byt < 4; ++byt) {
                float fa = (float)((aw[wi] >> (8 * byt)) & 0xffu);  // v_cvt_f32_ubyteN
                float fb = (float)((bw[wi] >> (8 * byt)) & 0xffu);
                float s = fmaxf(fmaf(fb, r, fa) - c, 0.f);
                p = fmaf(s, w2f[wi * 4 + byt], p);
            }
        }
        p += __shfl_xor(p, 1);
        p += __shfl_xor(p, 2);
        if (sl == 0) out[e] = fmaf(su, p, bias2);
    }
}

__global__ __launch_bounds__(256, 4) void edge_kernel(
    const long long* __restrict__ ei, const unsigned char* __restrict__ Aq,
    const unsigned char* __restrict__ Bq, const float* __restrict__ sA,
    const float* __restrict__ sB, const float* __restrict__ W2,
    const float* __restrict__ b2, float* __restrict__ out) {
    const int lane = threadIdx.x & 63;
    const int eg = lane >> 2;     // edge group 0..15 within wave
    const int sl = lane & 3;      // sub-lane within edge
    const float bias2 = b2[0];

    // int64-vs-int32 edge_index robustness probe (values < 1e5 -> hi words 0)
    const unsigned int hi = reinterpret_cast<const unsigned int*>(ei)[2 * lane + 1];
    const bool is64 = (__ballot(hi != 0) == 0ull);

    const int wid = (int)(((unsigned)(blockIdx.x * blockDim.x + threadIdx.x)) >> 6);
    const int nwaves = (int)(((unsigned)(gridDim.x * blockDim.x)) >> 6);

    if (is64) edge_loop<true>(ei, Aq, Bq, sA, sB, W2, bias2, out, wid, nwaves, eg, sl);
    else      edge_loop<false>(ei, Aq, Bq, sA, sB, W2, bias2, out, wid, nwaves, eg, sl);
}

extern "C" void kernel_launch(void* const* d_in, const int* in_sizes, int n_in,
                              void* d_out, int out_size, void* d_ws, size_t ws_size,
                              hipStream_t stream) {
    const float* x = (const float*)d_in[0];
    const long long* ei = (const long long*)d_in[1];
    const float* W1 = (const float*)d_in[2];
    const float* b1 = (const float*)d_in[3];
    const float* W2 = (const float*)d_in[4];
    const float* b2 = (const float*)d_in[5];
    float* out = (float*)d_out;

    unsigned char* Aq = (unsigned char*)d_ws;
    unsigned char* Bq = (unsigned char*)d_ws + BQ_OFF;
    float* sA = (float*)((char*)d_ws + SA_OFF);
    float* sB = (float*)((char*)d_ws + SB_OFF);

    dim3 g1(PRE_BLKX, 2);
    precompute_kernel<<<g1, 256, 0, stream>>>(x, W1, b1, Aq, Bq, sA, sB);
    edge_kernel<<<2048, 256, 0, stream>>>(ei, Aq, Bq, sA, sB, W2, b2, out);
}

// Round 14
// 171.916 us; speedup vs baseline: 1.0415x; 1.0249x over previous
//
#include <hip/hip_runtime.h>
#include <hip/hip_bf16.h>

#define N_NODES 100000
#define N_EDGES 1600000
#define NT_TILES 1563          // ceil(N_NODES/64)
#define PRE_BLKX 384           // 384*2 = 768 blocks = EXACTLY 3 blocks/CU
                               // residency (52.2 KB LDS) -> no serial 2nd
                               // round (R8/R9's 784 blocks had a 16-block
                               // tail ~= a full extra round)

// ws layout: Aq @0 (12.8 MB) | Bq @12.8M (12.8 MB) | sA @25.6M | sB @26.0M
#define BQ_OFF 12800000
#define SA_OFF 25600000
#define SB_OFF 26000000

typedef __attribute__((ext_vector_type(8))) short short8v;   // 8 bf16 = 4 VGPRs
typedef __attribute__((ext_vector_type(4))) float float4v;   // MFMA C/D

// ---------- bf16 helpers ----------
__device__ __forceinline__ unsigned short f2bf(float f) {
    unsigned int u = __float_as_uint(f);
    u += 0x7fffu + ((u >> 16) & 1u);   // round-to-nearest-even
    return (unsigned short)(u >> 16);
}
__device__ __forceinline__ unsigned int pack2bf(float a, float b) {
    return (unsigned int)f2bf(a) | ((unsigned int)f2bf(b) << 16);
}
__device__ __forceinline__ float2 bfpair(unsigned int w) {
    return float2{__uint_as_float(w << 16), __uint_as_float(w & 0xffff0000u)};
}
// magic-add quantize: biased uint8 (round(f*inv)+128) in the LOW BYTE, RNE.
#define MAGICB 12583040.0f     // 2^23 + 2^22 + 128
__device__ __forceinline__ unsigned int qmagic(float f, float inv) {
    return __float_as_uint(fmaf(f, inv, MAGICB));
}

// ---------------------------------------------------------------------------
// Phase 1 (MFMA, persistent node-loop) + biased-uint8 row quantization:
//   by==0: Aq[n][c] = q128(x[n]@W1[c,:128] + b1[c]),  sA[n] = rowmax/127
//   by==1: Bq[n][c] = q128(x[n]@W1[c,128:]),          sB[n] = rowmax/127
// R11 measured-best structure (W staged once/block in LDS, 4-tile node loop,
// x prefetch in regs, LDS-staged quant epilogue, grid 384x2 -> no residency
// tail). Beats all four attempted restructures (R10/R12/R13). LDS strides
// 136/132: 2-way bank aliasing on hot b128 reads = free (m136).
// 52.2 KB -> 3 blocks/CU.
// ---------------------------------------------------------------------------
__global__ __launch_bounds__(256) void precompute_kernel(
    const float* __restrict__ x, const float* __restrict__ W1,
    const float* __restrict__ b1, unsigned char* __restrict__ Aq,
    unsigned char* __restrict__ Bq, float* __restrict__ sA,
    float* __restrict__ sB) {
    __shared__ unsigned short wlds[128 * 136];
    __shared__ unsigned short xlds[64 * 136];   // input tile AND acc staging

    const int tid = threadIdx.x;
    const int by = blockIdx.y;            // 0: A-half (+b1), 1: B-half
    unsigned char* __restrict__ Q = by ? Bq : Aq;
    float* __restrict__ S = by ? sB : sA;

    const int wave = tid >> 6;
    const int lane = tid & 63;
    const int quad = lane >> 4;
    const int l15 = lane & 15;

    float4 b1v[2];
#pragma unroll
    for (int j = 0; j < 2; ++j)
        b1v[j] = *reinterpret_cast<const float4*>(b1 + wave * 32 + j * 16 + quad * 4);

    // ---- stage W half ONCE: W1[jl][by*128 + 0..127] -> bf16
#pragma unroll
    for (int i = 0; i < 16; ++i) {
        int fi = tid + i * 256;
        int jl = fi >> 5, c4 = fi & 31;
        float4 w4 = reinterpret_cast<const float4*>(W1)[(size_t)jl * 64 + by * 32 + c4];
        unsigned int* d = reinterpret_cast<unsigned int*>(&wlds[jl * 136 + c4 * 4]);
        d[0] = pack2bf(w4.x, w4.y);
        d[1] = pack2bf(w4.z, w4.w);
    }

    // ---- prologue: first tile's x into regs
    float4 xr[8];
    int t = blockIdx.x;
#pragma unroll
    for (int i = 0; i < 8; ++i) {
        int fi = tid + i * 256;
        int n = fi >> 5, c4 = fi & 31;
        int nn = t * 64 + n; nn = nn < N_NODES ? nn : N_NODES - 1;
        xr[i] = reinterpret_cast<const float4*>(x)[(size_t)nn * 32 + c4];
    }

    for (; t < NT_TILES; t += PRE_BLKX) {
        __syncthreads();   // prev epilogue's LDS reads done (covers W too)
#pragma unroll
        for (int i = 0; i < 8; ++i) {
            int fi = tid + i * 256;
            int n = fi >> 5, c4 = fi & 31;
            unsigned int* d = reinterpret_cast<unsigned int*>(&xlds[n * 136 + c4 * 4]);
            d[0] = pack2bf(xr[i].x, xr[i].y);
            d[1] = pack2bf(xr[i].z, xr[i].w);
        }
        __syncthreads();

        const int tn = t + PRE_BLKX;
        if (tn < NT_TILES) {
#pragma unroll
            for (int i = 0; i < 8; ++i) {
                int fi = tid + i * 256;
                int n = fi >> 5, c4 = fi & 31;
                int nn = tn * 64 + n; nn = nn < N_NODES ? nn : N_NODES - 1;
                xr[i] = reinterpret_cast<const float4*>(x)[(size_t)nn * 32 + c4];
            }
        }

        float4v acc[4][2];
#pragma unroll
        for (int i = 0; i < 4; ++i)
#pragma unroll
            for (int j = 0; j < 2; ++j) acc[i][j] = float4v{0.f, 0.f, 0.f, 0.f};

#pragma unroll
        for (int s = 0; s < 4; ++s) {
            const int k0 = s * 32 + quad * 8;
            short8v wf[2], xf[4];
#pragma unroll
            for (int j = 0; j < 2; ++j)
                wf[j] = *reinterpret_cast<const short8v*>(&wlds[(wave * 32 + j * 16 + l15) * 136 + k0]);
#pragma unroll
            for (int i = 0; i < 4; ++i)
                xf[i] = *reinterpret_cast<const short8v*>(&xlds[(i * 16 + l15) * 136 + k0]);
#pragma unroll
            for (int i = 0; i < 4; ++i)
#pragma unroll
                for (int j = 0; j < 2; ++j)
                    acc[i][j] = __builtin_amdgcn_mfma_f32_16x16x32_bf16(wf[j], xf[i], acc[i][j], 0, 0, 0);
        }
        __syncthreads();   // all xlds input reads done -> reuse as staging

        // ---- acc (+b1) -> LDS staging, bf16, stride 132 shorts
#pragma unroll
        for (int i = 0; i < 4; ++i) {
            const int nl = i * 16 + l15;
#pragma unroll
            for (int j = 0; j < 2; ++j) {
                const int colb = wave * 32 + j * 16 + quad * 4;
                float r0 = acc[i][j][0], r1 = acc[i][j][1];
                float r2 = acc[i][j][2], r3 = acc[i][j][3];
                if (by == 0) {
                    r0 += b1v[j].x; r1 += b1v[j].y;
                    r2 += b1v[j].z; r3 += b1v[j].w;
                }
                uint2 st = {pack2bf(r0, r1), pack2bf(r2, r3)};
                *reinterpret_cast<uint2*>(&xlds[nl * 132 + colb]) = st;
            }
        }
        __syncthreads();

        // ---- per-row max + magic quantize; thread = (row = tid>>2, part = tid&3)
        const int row = tid >> 2, part = tid & 3;
        const int n = t * 64 + row;
        uint4 wv[4];
#pragma unroll
        for (int q = 0; q < 4; ++q)
            wv[q] = *reinterpret_cast<const uint4*>(&xlds[row * 132 + part * 32 + q * 8]);

        float m = 1e-6f;
#pragma unroll
        for (int q = 0; q < 4; ++q) {
            unsigned int ws[4] = {wv[q].x, wv[q].y, wv[q].z, wv[q].w};
#pragma unroll
            for (int w = 0; w < 4; ++w) {
                float2 f = bfpair(ws[w]);
                m = fmaxf(m, fmaxf(fabsf(f.x), fabsf(f.y)));
            }
        }
        m = fmaxf(m, __shfl_xor(m, 1));   // quad (4 parts of one row) reduce
        m = fmaxf(m, __shfl_xor(m, 2));
        const float inv = 127.0f / m;

        unsigned int ob[8];
#pragma unroll
        for (int q = 0; q < 4; ++q) {
            unsigned int ws[4] = {wv[q].x, wv[q].y, wv[q].z, wv[q].w};
#pragma unroll
            for (int w = 0; w < 2; ++w) {
                float2 f0 = bfpair(ws[2 * w + 0]);
                float2 f1 = bfpair(ws[2 * w + 1]);
                unsigned int q0 = qmagic(f0.x, inv), q1 = qmagic(f0.y, inv);
                unsigned int q2 = qmagic(f1.x, inv), q3 = qmagic(f1.y, inv);
                ob[q * 2 + w] = (q0 & 0xffu) | ((q1 & 0xffu) << 8) |
                                ((q2 & 0xffu) << 16) | (q3 << 24);
            }
        }
        if (n < N_NODES) {
            uint4 s0 = {ob[0], ob[1], ob[2], ob[3]};
            uint4 s1 = {ob[4], ob[5], ob[6], ob[7]};
            uint4* dst = reinterpret_cast<uint4*>(Q + (size_t)n * 128 + part * 32);
            dst[0] = s0;
            dst[1] = s1;
            if (part == 0) S[n] = m * (1.0f / 127.0f);
        }
    }
}

// ---------------------------------------------------------------------------
// Phase 2: out[e] = W2 . relu(dq(Aq[u]) + dq(Bq[v])) + b2
// Biased uint8: relu(A+B) = su * max(fma(ub, r, ua) - c, 0), r = sv/su,
// c = 128(1+r); su applied once after the 4-lane reduction.
// 4 lanes/edge, 16 edges/wave-iter, 8x16-B gathers in flight.
// __launch_bounds__(256,4): R8/R10-verified — (256,8) raised WRITE_SIZE
// 6.4->21 MB via partial-line out writebacks (R9 regression).
// Parked at the compulsory per-XCD fetch floor (~189 MB @ ~3.2 TB/s).
// ---------------------------------------------------------------------------
template <bool IS64>
__device__ __forceinline__ void edge_loop(
    const long long* __restrict__ ei, const unsigned char* __restrict__ Aq,
    const unsigned char* __restrict__ Bq, const float* __restrict__ sA,
    const float* __restrict__ sB, const float* __restrict__ W2, float bias2,
    float* __restrict__ out, int wid, int nwaves, int eg, int sl) {
    const int k0 = sl * 32;              // feature base for this lane
    float w2f[32];
#pragma unroll
    for (int j = 0; j < 8; ++j)
        *reinterpret_cast<float4*>(&w2f[j * 4]) =
            *reinterpret_cast<const float4*>(W2 + k0 + j * 4);
    const int* e32 = reinterpret_cast<const int*>(ei);

    for (int base = wid * 16; base < N_EDGES; base += nwaves * 16) {
        const int e = base + eg;          // N_EDGES % 16 == 0 -> in range
        int u, v;
        if (IS64) { u = (int)ei[e]; v = (int)ei[N_EDGES + e]; }
        else      { u = e32[e];     v = e32[N_EDGES + e]; }

        const uint4* pa = reinterpret_cast<const uint4*>(Aq + (unsigned)u * 128 + k0);
        const uint4* pb = reinterpret_cast<const uint4*>(Bq + (unsigned)v * 128 + k0);
        uint4 a0 = pa[0], a1 = pa[1];
        uint4 b0 = pb[0], b1w = pb[1];
        const float su = sA[u];
        const float sv = sB[v];
        const float r = sv * __builtin_amdgcn_rcpf(su);   // su > 0 by construction
        const float c = fmaf(r, 128.0f, 128.0f);          // 128*(1+r)

        unsigned int aw[8] = {a0.x, a0.y, a0.z, a0.w, a1.x, a1.y, a1.z, a1.w};
        unsigned int bw[8] = {b0.x, b0.y, b0.z, b0.w, b1w.x, b1w.y, b1w.z, b1w.w};

        float p = 0.f;
#pragma unroll
        for (int wi = 0; wi < 8; ++wi) {
#pragma unroll
            for (int byt = 0; byt < 4; ++byt) {
                float fa = (float)((aw[wi] >> (8 * byt)) & 0xffu);  // v_cvt_f32_ubyteN
                float fb = (float)((bw[wi] >> (8 * byt)) & 0xffu);
                float s = fmaxf(fmaf(fb, r, fa) - c, 0.f);
                p = fmaf(s, w2f[wi * 4 + byt], p);
            }
        }
        p += __shfl_xor(p, 1);
        p += __shfl_xor(p, 2);
        if (sl == 0) out[e] = fmaf(su, p, bias2);
    }
}

__global__ __launch_bounds__(256, 4) void edge_kernel(
    const long long* __restrict__ ei, const unsigned char* __restrict__ Aq,
    const unsigned char* __restrict__ Bq, const float* __restrict__ sA,
    const float* __restrict__ sB, const float* __restrict__ W2,
    const float* __restrict__ b2, float* __restrict__ out) {
    const int lane = threadIdx.x & 63;
    const int eg = lane >> 2;     // edge group 0..15 within wave
    const int sl = lane & 3;      // sub-lane within edge
    const float bias2 = b2[0];

    // int64-vs-int32 edge_index robustness probe (values < 1e5 -> hi words 0)
    const unsigned int hi = reinterpret_cast<const unsigned int*>(ei)[2 * lane + 1];
    const bool is64 = (__ballot(hi != 0) == 0ull);

    const int wid = (int)(((unsigned)(blockIdx.x * blockDim.x + threadIdx.x)) >> 6);
    const int nwaves = (int)(((unsigned)(gridDim.x * blockDim.x)) >> 6);

    if (is64) edge_loop<true>(ei, Aq, Bq, sA, sB, W2, bias2, out, wid, nwaves, eg, sl);
    else      edge_loop<false>(ei, Aq, Bq, sA, sB, W2, bias2, out, wid, nwaves, eg, sl);
}

extern "C" void kernel_launch(void* const* d_in, const int* in_sizes, int n_in,
                              void* d_out, int out_size, void* d_ws, size_t ws_size,
                              hipStream_t stream) {
    const float* x = (const float*)d_in[0];
    const long long* ei = (const long long*)d_in[1];
    const float* W1 = (const float*)d_in[2];
    const float* b1 = (const float*)d_in[3];
    const float* W2 = (const float*)d_in[4];
    const float* b2 = (const float*)d_in[5];
    float* out = (float*)d_out;

    unsigned char* Aq = (unsigned char*)d_ws;
    unsigned char* Bq = (unsigned char*)d_ws + BQ_OFF;
    float* sA = (float*)((char*)d_ws + SA_OFF);
    float* sB = (float*)((char*)d_ws + SB_OFF);

    dim3 g1(PRE_BLKX, 2);
    precompute_kernel<<<g1, 256, 0, stream>>>(x, W1, b1, Aq, Bq, sA, sB);
    edge_kernel<<<2048, 256, 0, stream>>>(ei, Aq, Bq, sA, sB, W2, b2, out);
}